// Round 2
// baseline (88.684 us; speedup 1.0000x reference)
//
#include <hip/hip_runtime.h>

// SSIM loss: 2x2 avg-pool + separable 11x11 Gaussian + SSIM + mean, row-sliding form.
// x,y f32 [32,3,512,512]. Pooled 256x256/plane; conv VALID out 246x246; 96 planes.
// One thread per pooled column (256), one block per (plane, 16-row output strip).
// Horizontal sums live in an 11-deep register ring (full unroll -> static indices);
// vertical pass is register-only. LDS holds just one double-buffered pooled row
// (5 planes: x, y, x^2, y^2, xy).

#define KS 11
#define H  16                 // output rows per strip
#define NSTRIP 16             // 16*16 = 256 >= 246
#define NPLANE 96
#define NBLK (NSTRIP * NPLANE)   // 1536
#define BUFW 272              // 256 + >=10 halo pad (zeros)
#define OUTD 246

__global__ __launch_bounds__(256) void ssim_strip(const float* __restrict__ x,
                                                  const float* __restrict__ y,
                                                  double* __restrict__ partial) {
    __shared__ float sx[2][BUFW], sy[2][BUFW];
    __shared__ float sxx[2][BUFW], syy[2][BUFW], sxy[2][BUFW];
    __shared__ float wred[4];

    const int c = threadIdx.x;                 // pooled column 0..255
    const int strip = blockIdx.x;
    const int plane = blockIdx.y;
    const int r0 = strip * H;
    const float* xp = x + (size_t)plane * 512 * 512;
    const float* yp = y + (size_t)plane * 512 * 512;

    // normalized separable Gaussian weights
    float w[KS];
    {
        float s = 0.f;
        #pragma unroll
        for (int i = 0; i < KS; ++i) {
            float d = (float)i - 5.f;
            w[i] = __expf(-d * d / 4.5f);      // 2*sigma^2 = 4.5
            s += w[i];
        }
        float inv = 1.f / s;
        #pragma unroll
        for (int i = 0; i < KS; ++i) w[i] *= inv;
    }

    // zero the halo pad once (covers both buffers; first barrier orders it)
    if (c < BUFW - 256) {
        #pragma unroll
        for (int b = 0; b < 2; ++b) {
            sx[b][256 + c] = 0.f; sy[b][256 + c] = 0.f;
            sxx[b][256 + c] = 0.f; syy[b][256 + c] = 0.f; sxy[b][256 + c] = 0.f;
        }
    }

    float rmx[KS], rmy[KS], rxx[KS], ryy[KS], rxy[KS];
    float local = 0.f;
    const float c1 = 1e-4f, c2 = 9e-4f;

    #pragma unroll
    for (int i = 0; i < H + KS - 1; ++i) {     // 26 iterations, fully unrolled
        int pr = r0 + i;                        // pooled row
        if (pr > 255) pr = 255;                 // clamp (results discarded)

        // 2x2 pool from global (coalesced float2 per lane)
        const float2 a0 = *(const float2*)(xp + (size_t)(2 * pr) * 512 + 2 * c);
        const float2 a1 = *(const float2*)(xp + (size_t)(2 * pr + 1) * 512 + 2 * c);
        const float2 b0 = *(const float2*)(yp + (size_t)(2 * pr) * 512 + 2 * c);
        const float2 b1 = *(const float2*)(yp + (size_t)(2 * pr + 1) * 512 + 2 * c);
        float px = (a0.x + a0.y + a1.x + a1.y) * 0.25f;
        float py = (b0.x + b0.y + b1.x + b1.y) * 0.25f;

        const int buf = i & 1;
        sx[buf][c] = px;        sy[buf][c] = py;
        sxx[buf][c] = px * px;  syy[buf][c] = py * py;  sxy[buf][c] = px * py;
        __syncthreads();        // write(buf) -> barrier -> read(buf); WAR on buf^1 is
                                // ordered by this same barrier (read i-1 < bar(i) < write i+1)

        // horizontal 11-tap on 5 planes
        float hmx = 0.f, hmy = 0.f, hxx = 0.f, hyy = 0.f, hxy = 0.f;
        #pragma unroll
        for (int k = 0; k < KS; ++k) {
            float wk = w[k];
            hmx += wk * sx[buf][c + k];
            hmy += wk * sy[buf][c + k];
            hxx += wk * sxx[buf][c + k];
            hyy += wk * syy[buf][c + k];
            hxy += wk * sxy[buf][c + k];
        }
        const int slot = i % KS;                // compile-time after unroll
        rmx[slot] = hmx; rmy[slot] = hmy; rxx[slot] = hxx; ryy[slot] = hyy; rxy[slot] = hxy;

        if (i >= KS - 1) {
            // vertical 11-tap, register-only
            float mx = 0.f, my = 0.f, xx = 0.f, yy = 0.f, xy = 0.f;
            #pragma unroll
            for (int k = 0; k < KS; ++k) {
                const int s = (i - (KS - 1) + k) % KS;   // compile-time
                float wk = w[k];
                mx += wk * rmx[s]; my += wk * rmy[s];
                xx += wk * rxx[s]; yy += wk * ryy[s]; xy += wk * rxy[s];
            }
            const int ro = r0 + i - (KS - 1);
            if (ro < OUTD && c < OUTD) {
                float mxx = mx * mx, myy = my * my, mxy = mx * my;
                float vxx = xx - mxx, vyy = yy - myy, vxy = xy - mxy;
                float cs = (2.f * vxy + c2) / (vxx + vyy + c2);
                local += (2.f * mxy + c1) / (mxx + myy + c1) * cs;
            }
        }
    }

    // block reduction
    #pragma unroll
    for (int off = 32; off > 0; off >>= 1)
        local += __shfl_down(local, off, 64);
    if ((c & 63) == 0) wred[c >> 6] = local;
    __syncthreads();
    if (c == 0) {
        int bid = blockIdx.y * gridDim.x + blockIdx.x;
        partial[bid] = (double)(wred[0] + wred[1] + wred[2] + wred[3]);
    }
}

__global__ __launch_bounds__(256) void ssim_finalize(const double* __restrict__ partial,
                                                     float* __restrict__ out) {
    const int tid = threadIdx.x;
    double s = 0.0;
    for (int i = tid; i < NBLK; i += 256) s += partial[i];
    #pragma unroll
    for (int off = 32; off > 0; off >>= 1)
        s += __shfl_down(s, off, 64);
    __shared__ double sd[4];
    if ((tid & 63) == 0) sd[tid >> 6] = s;
    __syncthreads();
    if (tid == 0) {
        double total = sd[0] + sd[1] + sd[2] + sd[3];
        const double n = (double)NPLANE * OUTD * OUTD;
        out[0] = (float)(1.0 - total / n);
    }
}

extern "C" void kernel_launch(void* const* d_in, const int* in_sizes, int n_in,
                              void* d_out, int out_size, void* d_ws, size_t ws_size,
                              hipStream_t stream) {
    const float* x = (const float*)d_in[0];
    const float* y = (const float*)d_in[1];
    float* out = (float*)d_out;
    double* partial = (double*)d_ws;   // 1536 * 8 = 12 KiB

    dim3 grid(NSTRIP, NPLANE, 1);
    ssim_strip<<<grid, 256, 0, stream>>>(x, y, partial);
    ssim_finalize<<<1, 256, 0, stream>>>(partial, out);
}

// Round 3
// 65.571 us; speedup vs baseline: 1.3525x; 1.3525x over previous
//
#include <hip/hip_runtime.h>

// SSIM loss, wave-autonomous vertical-first form.
// x,y f32 [32,3,512,512] -> pooled 256x256/plane -> separable 11x11 Gaussian ->
// SSIM map 246x246 -> 1 - mean.
// Each WAVE owns (plane, 12-row output strip); 4 pooled cols/lane * 64 lanes = 256 cols.
// Ring of raw pooled rows (2 planes x 11 deep x 4 cols = 88 VGPR, static idx + rotation).
// Vertical 11-tap in registers -> 5 V-sum planes staged to wave-private LDS (b128) ->
// horizontal 11-tap from 4x aligned ds_read_b128 per plane. No __syncthreads anywhere.

#define KS 11
#define H 12
#define ROWS (H + KS - 1)        // 22 pooled rows per strip
#define NSTRIP 21                // 21*12 = 252 >= 246
#define NPLANE 96
#define NWAVE (NPLANE * NSTRIP)  // 2016
#define NBLOCK (NWAVE / 4)       // 504
#define OUTD 246
#define BUFW 272                 // 256 + 16 pad cols (zeroed)
#define C1V 1e-4f
#define C2V 9e-4f

__device__ __forceinline__ void load_pool(const float* __restrict__ xp,
                                          const float* __restrict__ yp,
                                          int r0, int i, int lane,
                                          float (&px)[4], float (&py)[4]) {
    int pr = r0 + i; pr = pr > 255 ? 255 : pr;   // clamp; clamped rows feed masked outputs only
    const float* xr = xp + (size_t)(2 * pr) * 512 + 8 * lane;
    const float* yr = yp + (size_t)(2 * pr) * 512 + 8 * lane;
    float4 a0 = *(const float4*)xr;
    float4 a1 = *(const float4*)(xr + 4);
    float4 b0 = *(const float4*)(xr + 512);
    float4 b1 = *(const float4*)(xr + 516);
    float4 c0 = *(const float4*)yr;
    float4 c1 = *(const float4*)(yr + 4);
    float4 d0 = *(const float4*)(yr + 512);
    float4 d1 = *(const float4*)(yr + 516);
    px[0] = (a0.x + a0.y + b0.x + b0.y) * 0.25f;
    px[1] = (a0.z + a0.w + b0.z + b0.w) * 0.25f;
    px[2] = (a1.x + a1.y + b1.x + b1.y) * 0.25f;
    px[3] = (a1.z + a1.w + b1.z + b1.w) * 0.25f;
    py[0] = (c0.x + c0.y + d0.x + d0.y) * 0.25f;
    py[1] = (c0.z + c0.w + d0.z + d0.w) * 0.25f;
    py[2] = (c1.x + c1.y + d1.x + d1.y) * 0.25f;
    py[3] = (c1.z + c1.w + d1.z + d1.w) * 0.25f;
}

__device__ __forceinline__ void step_row(float* vb, const float (&wt)[KS],
                                         float (&rx)[KS][4], float (&ry)[KS][4],
                                         const float (&px)[4], const float (&py)[4],
                                         int lane, int ro, float& local) {
    // push newest row into slot KS-1
    #pragma unroll
    for (int c = 0; c < 4; ++c) { rx[KS - 1][c] = px[c]; ry[KS - 1][c] = py[c]; }

    // vertical 11-tap, products on the fly (all register, static idx)
    float vmx[4] = {0,0,0,0}, vmy[4] = {0,0,0,0};
    float vxx[4] = {0,0,0,0}, vyy[4] = {0,0,0,0}, vxy[4] = {0,0,0,0};
    #pragma unroll
    for (int k = 0; k < KS; ++k) {
        float wk = wt[k];
        #pragma unroll
        for (int c = 0; c < 4; ++c) {
            float xv = rx[k][c], yv = ry[k][c];
            vmx[c] += wk * xv;       vmy[c] += wk * yv;
            vxx[c] += wk * xv * xv;  vyy[c] += wk * yv * yv;
            vxy[c] += wk * xv * yv;
        }
    }

    // stage 5 V-sum planes to wave-private LDS (b128, conflict-free)
    *(float4*)(vb + 0 * BUFW + 4 * lane) = make_float4(vmx[0], vmx[1], vmx[2], vmx[3]);
    *(float4*)(vb + 1 * BUFW + 4 * lane) = make_float4(vmy[0], vmy[1], vmy[2], vmy[3]);
    *(float4*)(vb + 2 * BUFW + 4 * lane) = make_float4(vxx[0], vxx[1], vxx[2], vxx[3]);
    *(float4*)(vb + 3 * BUFW + 4 * lane) = make_float4(vyy[0], vyy[1], vyy[2], vyy[3]);
    *(float4*)(vb + 4 * BUFW + 4 * lane) = make_float4(vxy[0], vxy[1], vxy[2], vxy[3]);
    __builtin_amdgcn_wave_barrier();   // pin order; intra-wave DS deps get waitcnt from compiler

    // horizontal 11-tap: window cols 4l..4l+13 via 4 aligned b128 per plane
    float hp[5][4];
    #pragma unroll
    for (int p = 0; p < 5; ++p) {
        const float* bp = vb + p * BUFW + 4 * lane;
        float4 q0 = *(const float4*)bp;
        float4 q1 = *(const float4*)(bp + 4);
        float4 q2 = *(const float4*)(bp + 8);
        float4 q3 = *(const float4*)(bp + 12);
        float win[16] = {q0.x, q0.y, q0.z, q0.w, q1.x, q1.y, q1.z, q1.w,
                         q2.x, q2.y, q2.z, q2.w, q3.x, q3.y, q3.z, q3.w};
        #pragma unroll
        for (int c = 0; c < 4; ++c) {
            float a = 0.f;
            #pragma unroll
            for (int j = 0; j < KS; ++j) a += wt[j] * win[c + j];
            hp[p][c] = a;
        }
    }

    if (ro < OUTD) {
        #pragma unroll
        for (int c = 0; c < 4; ++c) {
            int oc = 4 * lane + c;
            float mx = hp[0][c], my = hp[1][c];
            float mxx = mx * mx, myy = my * my, mxy = mx * my;
            float sxx = hp[2][c] - mxx, syy = hp[3][c] - myy, sxy = hp[4][c] - mxy;
            float num = (2.f * mxy + C1V) * (2.f * sxy + C2V);
            float den = (mxx + myy + C1V) * (sxx + syy + C2V);
            float ss = num / den;
            local += (oc < OUTD) ? ss : 0.f;
        }
    }

    // rotate ring (static, 80 movs)
    #pragma unroll
    for (int k = 0; k < KS - 1; ++k) {
        #pragma unroll
        for (int c = 0; c < 4; ++c) { rx[k][c] = rx[k + 1][c]; ry[k][c] = ry[k + 1][c]; }
    }
}

__global__ __launch_bounds__(256, 2) void ssim_wave(const float* __restrict__ x,
                                                    const float* __restrict__ y,
                                                    double* __restrict__ partial) {
    __shared__ float vbuf[4][2][5][BUFW];   // [wave][parity][plane][col] = 43.5 KB
    const int tid = threadIdx.x;
    const int wv = tid >> 6, lane = tid & 63;
    const int gid = blockIdx.x * 4 + wv;
    const int plane = gid / NSTRIP, strip = gid % NSTRIP;
    const int r0 = strip * H;
    const float* xp = x + (size_t)plane * (512 * 512);
    const float* yp = y + (size_t)plane * (512 * 512);

    float wt[KS];
    {
        float s = 0.f;
        #pragma unroll
        for (int i = 0; i < KS; ++i) {
            float d = (float)i - 5.f;
            wt[i] = expf(-d * d / 4.5f);   // 2*sigma^2 = 4.5
            s += wt[i];
        }
        float inv = 1.f / s;
        #pragma unroll
        for (int i = 0; i < KS; ++i) wt[i] *= inv;
    }

    // zero the 16 pad cols of both parity buffers (reads beyond col 255 feed masked outputs)
    if (lane < BUFW - 256) {
        #pragma unroll
        for (int b = 0; b < 2; ++b)
            #pragma unroll
            for (int p = 0; p < 5; ++p)
                vbuf[wv][b][p][256 + lane] = 0.f;
    }
    __builtin_amdgcn_wave_barrier();

    // prime ring: rows 0..9 -> slots 0..9
    float rx[KS][4], ry[KS][4];
    #pragma unroll
    for (int i = 0; i < KS - 1; ++i)
        load_pool(xp, yp, r0, i, lane, rx[i], ry[i]);

    float cpx[4], cpy[4], npx[4], npy[4];
    load_pool(xp, yp, r0, KS - 1, lane, cpx, cpy);
    float local = 0.f;

    #pragma unroll 1
    for (int i = KS - 1; i < ROWS; ++i) {
        load_pool(xp, yp, r0, i + 1, lane, npx, npy);   // prefetch next row (clamped at end)
        float* vb = &vbuf[wv][i & 1][0][0];
        step_row(vb, wt, rx, ry, cpx, cpy, lane, r0 + i - (KS - 1), local);
        #pragma unroll
        for (int c = 0; c < 4; ++c) { cpx[c] = npx[c]; cpy[c] = npy[c]; }
    }

    // wave reduce, one partial per wave
    #pragma unroll
    for (int off = 32; off > 0; off >>= 1)
        local += __shfl_down(local, off, 64);
    if (lane == 0) partial[gid] = (double)local;
}

__global__ __launch_bounds__(256) void ssim_finalize(const double* __restrict__ partial,
                                                     float* __restrict__ out) {
    const int tid = threadIdx.x;
    double s = 0.0;
    for (int i = tid; i < NWAVE; i += 256) s += partial[i];
    #pragma unroll
    for (int off = 32; off > 0; off >>= 1)
        s += __shfl_down(s, off, 64);
    __shared__ double sd[4];
    if ((tid & 63) == 0) sd[tid >> 6] = s;
    __syncthreads();
    if (tid == 0) {
        double total = sd[0] + sd[1] + sd[2] + sd[3];
        const double n = (double)NPLANE * OUTD * OUTD;   // 5,809,536
        out[0] = (float)(1.0 - total / n);
    }
}

extern "C" void kernel_launch(void* const* d_in, const int* in_sizes, int n_in,
                              void* d_out, int out_size, void* d_ws, size_t ws_size,
                              hipStream_t stream) {
    const float* x = (const float*)d_in[0];
    const float* y = (const float*)d_in[1];
    float* out = (float*)d_out;
    double* partial = (double*)d_ws;   // NWAVE * 8 = 16 KiB

    ssim_wave<<<NBLOCK, 256, 0, stream>>>(x, y, partial);
    ssim_finalize<<<1, 256, 0, stream>>>(partial, out);
}